// Round 2
// baseline (1340.257 us; speedup 1.0000x reference)
//
#include <hip/hip_runtime.h>
#include <hip/hip_bf16.h>
#include <stdint.h>

#define IN_CH 64
#define OUT_CH 128

// Each 256-thread block handles 2 rule entries; thread c in [0,128) computes
// output channel c of one entry: sum_i feats[in][i] * W[k][i][c], then
// atomicAdd into acc[out*128 + c].
__global__ void __launch_bounds__(256) scatter_gemm_kernel(
    const float* __restrict__ feats,
    const float* __restrict__ W,
    const int* __restrict__ in_idx,
    const int* __restrict__ out_idx,
    const int* __restrict__ mask,   // harness stores bool as int32
    float* __restrict__ acc,
    int R)
{
    const int nE = 9 * R;
    int e = blockIdx.x * 2 + (threadIdx.x >> 7);
    int c = threadIdx.x & 127;
    if (e >= nE) return;
    if (!mask[e]) return;

    int k = e / R;
    int in = in_idx[e];
    int out = out_idx[e];

    const float* __restrict__ f = feats + (size_t)in * IN_CH;
    const float* __restrict__ w = W + (size_t)k * IN_CH * OUT_CH + c;

    float s = 0.0f;
#pragma unroll 16
    for (int i = 0; i < IN_CH; ++i) {
        s += f[i] * w[i * OUT_CH];
    }
    atomicAdd(acc + (size_t)out * OUT_CH + c, s);
}

// Per-channel sum and sum-of-squares over n_out rows.
__global__ void __launch_bounds__(128) stats_kernel(
    const float* __restrict__ acc,
    float* __restrict__ sums,   // [256]: sums[0:128]=sum, sums[128:256]=sumsq
    int n_out)
{
    int c = threadIdx.x;  // 0..127
    float s = 0.0f, s2 = 0.0f;
    for (int r = blockIdx.x; r < n_out; r += gridDim.x) {
        float v = acc[(size_t)r * OUT_CH + c];
        s += v;
        s2 += v * v;
    }
    atomicAdd(&sums[c], s);
    atomicAdd(&sums[OUT_CH + c], s2);
}

// y = gamma*(x-mean)*rsqrt(var+eps)+beta, relu; in-place on d_out.
__global__ void __launch_bounds__(256) bn_relu_kernel(
    float* __restrict__ out,
    const float* __restrict__ sums,
    const float* __restrict__ gamma,
    const float* __restrict__ beta,
    int n_out)
{
    int idx = blockIdx.x * 256 + threadIdx.x;
    int total = n_out * OUT_CH;
    if (idx >= total) return;
    int c = idx & (OUT_CH - 1);
    float inv_n = 1.0f / (float)n_out;
    float mean = sums[c] * inv_n;
    float var = sums[OUT_CH + c] * inv_n - mean * mean;
    float v = out[idx];
    float y = gamma[c] * (v - mean) * rsqrtf(var + 1e-5f) + beta[c];
    out[idx] = fmaxf(y, 0.0f);
}

extern "C" void kernel_launch(void* const* d_in, const int* in_sizes, int n_in,
                              void* d_out, int out_size, void* d_ws, size_t ws_size,
                              hipStream_t stream) {
    const float* feats   = (const float*)d_in[0];
    const float* W       = (const float*)d_in[1];
    const float* gamma   = (const float*)d_in[2];
    const float* beta    = (const float*)d_in[3];
    const int*   in_idx  = (const int*)d_in[4];
    const int*   out_idx = (const int*)d_in[5];
    const int*   mask    = (const int*)d_in[6];   // bool stored as int32
    // d_in[7] = n_out scalar (device); we use out_size instead.

    const int R = in_sizes[4] / 9;
    const int n_out = out_size / OUT_CH;

    float* acc  = (float*)d_out;          // accumulate directly into output
    float* sums = (float*)d_ws;           // 256 floats

    // Zero accumulator and stats scratch.
    hipMemsetAsync(d_out, 0, (size_t)out_size * sizeof(float), stream);
    hipMemsetAsync(d_ws, 0, 2 * OUT_CH * sizeof(float), stream);

    // Scatter GEMM: 2 entries per block.
    {
        int nE = 9 * R;
        int blocks = (nE + 1) / 2;
        scatter_gemm_kernel<<<blocks, 256, 0, stream>>>(
            feats, W, in_idx, out_idx, mask, acc, R);
    }

    // Channel stats.
    stats_kernel<<<512, 128, 0, stream>>>(acc, sums, n_out);

    // BatchNorm + ReLU in place.
    {
        int total = n_out * OUT_CH;
        int blocks = (total + 255) / 256;
        bn_relu_kernel<<<blocks, 256, 0, stream>>>(acc, sums, gamma, beta, n_out);
    }
}

// Round 3
// 649.774 us; speedup vs baseline: 2.0627x; 2.0627x over previous
//
#include <hip/hip_runtime.h>
#include <hip/hip_bf16.h>
#include <stdint.h>

#define IN_CH 64
#define OUT_CH 128
#define ENTRIES_PER_BLOCK 128

// Zero d_out (n floats, n % 4 == 0) and the 256-float stats scratch.
__global__ void __launch_bounds__(256) zero_kernel(float4* __restrict__ out, int n4,
                                                   float* __restrict__ sums) {
    int idx = blockIdx.x * 256 + threadIdx.x;
    if (idx < n4) out[idx] = make_float4(0.f, 0.f, 0.f, 0.f);
    if (blockIdx.x == 0 && threadIdx.x < 2 * OUT_CH) sums[threadIdx.x] = 0.f;
}

// Block = 4 waves. Wave handles (k = blockIdx.y, half = waveId&1) and entry
// stream r = r0 + (waveId>>1), step 2. The wave's 64 W columns are loaded
// into 64 VGPRs once and reused across all entries. Per entry, indices and
// the feature row are wave-uniform -> scalar loads; inner loop is 64 fma.
__global__ void __launch_bounds__(256) scatter_gemm_kernel(
    const float* __restrict__ feats,
    const float* __restrict__ W,
    const int* __restrict__ in_idx,
    const int* __restrict__ out_idx,
    const int* __restrict__ mask,   // bool stored as int32
    float* __restrict__ acc,
    int R)
{
    const int lane = threadIdx.x & 63;
    const int waveId = threadIdx.x >> 6;
    const int half = waveId & 1;          // which 64 channels
    const int pair = waveId >> 1;         // which entry sub-stream (0 or 1)
    const int k = blockIdx.y;
    const int c = half * 64 + lane;       // this lane's output channel

    // Load this lane's W column into registers (reused across entries).
    float wreg[IN_CH];
    const float* __restrict__ wp = W + (size_t)k * IN_CH * OUT_CH + c;
#pragma unroll
    for (int i = 0; i < IN_CH; ++i) wreg[i] = wp[i * OUT_CH];

    const int r0 = blockIdx.x * ENTRIES_PER_BLOCK;
    const int rEnd = min(r0 + ENTRIES_PER_BLOCK, R);
    const int* __restrict__ maskK = mask + (size_t)k * R;
    const int* __restrict__ inK = in_idx + (size_t)k * R;
    const int* __restrict__ outK = out_idx + (size_t)k * R;

    for (int r = r0 + pair; r < rEnd; r += 2) {
        if (!__builtin_amdgcn_readfirstlane(maskK[r])) continue;
        int in = __builtin_amdgcn_readfirstlane(inK[r]);
        int out = __builtin_amdgcn_readfirstlane(outK[r]);
        const float* __restrict__ f = feats + (size_t)in * IN_CH;
        float s = 0.f, s1 = 0.f;
#pragma unroll
        for (int i = 0; i < IN_CH; i += 2) {
            s = fmaf(wreg[i], f[i], s);
            s1 = fmaf(wreg[i + 1], f[i + 1], s1);
        }
        atomicAdd(acc + (size_t)out * OUT_CH + c, s + s1);
    }
}

// Per-channel sum and sum-of-squares over n_out rows.
__global__ void __launch_bounds__(128) stats_kernel(
    const float* __restrict__ acc,
    float* __restrict__ sums,   // [256]: sums[0:128]=sum, sums[128:256]=sumsq
    int n_out)
{
    int c = threadIdx.x;  // 0..127
    float s = 0.0f, s2 = 0.0f;
    for (int r = blockIdx.x; r < n_out; r += gridDim.x) {
        float v = acc[(size_t)r * OUT_CH + c];
        s += v;
        s2 += v * v;
    }
    atomicAdd(&sums[c], s);
    atomicAdd(&sums[OUT_CH + c], s2);
}

// y = gamma*(x-mean)*rsqrt(var+eps)+beta, relu; in-place, float4-vectorized.
__global__ void __launch_bounds__(256) bn_relu_kernel(
    float4* __restrict__ out,
    const float* __restrict__ sums,
    const float* __restrict__ gamma,
    const float* __restrict__ beta,
    int total4, float inv_n)
{
    int idx = blockIdx.x * 256 + threadIdx.x;
    if (idx >= total4) return;
    int c0 = (idx & 31) * 4;  // channel of .x component
    float4 v = out[idx];
    float r[4] = {v.x, v.y, v.z, v.w};
#pragma unroll
    for (int j = 0; j < 4; ++j) {
        int c = c0 + j;
        float mean = sums[c] * inv_n;
        float var = sums[OUT_CH + c] * inv_n - mean * mean;
        float scale = gamma[c] * rsqrtf(var + 1e-5f);
        float y = (r[j] - mean) * scale + beta[c];
        r[j] = fmaxf(y, 0.0f);
    }
    out[idx] = make_float4(r[0], r[1], r[2], r[3]);
}

extern "C" void kernel_launch(void* const* d_in, const int* in_sizes, int n_in,
                              void* d_out, int out_size, void* d_ws, size_t ws_size,
                              hipStream_t stream) {
    const float* feats   = (const float*)d_in[0];
    const float* W       = (const float*)d_in[1];
    const float* gamma   = (const float*)d_in[2];
    const float* beta    = (const float*)d_in[3];
    const int*   in_idx  = (const int*)d_in[4];
    const int*   out_idx = (const int*)d_in[5];
    const int*   mask    = (const int*)d_in[6];   // bool stored as int32
    // d_in[7] = n_out scalar (device); we use out_size instead.

    const int R = in_sizes[4] / 9;
    const int n_out = out_size / OUT_CH;

    float* acc  = (float*)d_out;          // accumulate directly into output
    float* sums = (float*)d_ws;           // 256 floats

    // Zero accumulator + stats scratch with a fast float4 fill.
    {
        int n4 = out_size / 4;
        int blocks = (n4 + 255) / 256;
        zero_kernel<<<blocks, 256, 0, stream>>>((float4*)acc, n4, sums);
    }

    // Scatter GEMM: W held in VGPRs per wave, scalar f loads, atomic scatter.
    {
        dim3 grid((R + ENTRIES_PER_BLOCK - 1) / ENTRIES_PER_BLOCK, 9);
        scatter_gemm_kernel<<<grid, 256, 0, stream>>>(
            feats, W, in_idx, out_idx, mask, acc, R);
    }

    // Channel stats.
    stats_kernel<<<2048, 128, 0, stream>>>(acc, sums, n_out);

    // BatchNorm + ReLU in place (float4).
    {
        int total4 = out_size / 4;
        int blocks = (total4 + 255) / 256;
        bn_relu_kernel<<<blocks, 256, 0, stream>>>(
            (float4*)acc, sums, gamma, beta, total4, 1.0f / (float)n_out);
    }
}